// Round 1
// baseline (1280.006 us; speedup 1.0000x reference)
//
#include <hip/hip_runtime.h>
#include <cmath>

#define NB 2
#define NN 2048
#define ND 128
#define NH 8
#define NL 3
#define NV 32
#define NDH 16
#define ATT_SCALE 0.25f  /* 1/sqrt(16) */
#define NEGV -1e9f
#define LN_EPS 1e-5f

// ---------------- embedding select ----------------
__global__ void embed_kernel(const float* __restrict__ atom_embed,
                             const float* __restrict__ cons_embed,
                             const int* __restrict__ is_atom,
                             const int* __restrict__ atom_id,
                             float* __restrict__ x) {
  int idx = blockIdx.x * 256 + threadIdx.x;       // over 4096*128
  int row = idx >> 7, d = idx & 127;
  int id = atom_id[row];
  id = id < 0 ? 0 : (id > NV - 1 ? NV - 1 : id);
  float e = is_atom[row] ? atom_embed[id * ND + d] : cons_embed[d];
  x[idx] = e;
}

// ---------------- layernorm over D=128, one wave per row ----------------
__global__ __launch_bounds__(256) void ln_kernel(const float* __restrict__ in,
                                                 float* __restrict__ out,
                                                 const float* __restrict__ g,
                                                 const float* __restrict__ bt) {
  int row = blockIdx.x * 4 + (threadIdx.x >> 6);
  int lane = threadIdx.x & 63;
  const float* xr = in + (size_t)row * ND;
  float2 v = *(const float2*)&xr[lane * 2];
  float s1 = v.x + v.y;
  float s2 = v.x * v.x + v.y * v.y;
#pragma unroll
  for (int m = 32; m >= 1; m >>= 1) {
    s1 += __shfl_xor(s1, m, 64);
    s2 += __shfl_xor(s2, m, 64);
  }
  float mean = s1 * (1.0f / ND);
  float var = s2 * (1.0f / ND) - mean * mean;
  float rstd = rsqrtf(var + LN_EPS);
  float2 gg = *(const float2*)&g[lane * 2];
  float2 bb = *(const float2*)&bt[lane * 2];
  float2 o;
  o.x = (v.x - mean) * rstd * gg.x + bb.x;
  o.y = (v.y - mean) * rstd * gg.y + bb.y;
  *(float2*)&out[(size_t)row * ND + lane * 2] = o;
}

// ---------------- fp32 SGEMM: C[M,Nc] = X[M,K] @ W[Nc,K]^T + bias (+res)(gelu) ----------------
__global__ __launch_bounds__(256) void sgemm_kernel(
    const float* __restrict__ X, const float* __restrict__ W,
    const float* __restrict__ bias, const float* __restrict__ res,
    float* __restrict__ C, int M, int Nc, int K, int act) {
  __shared__ float As[8][64];
  __shared__ float Bs[8][64];
  int m0 = blockIdx.y * 64, n0 = blockIdx.x * 64;
  int t = threadIdx.x, tx = t & 15, ty = t >> 4;
  float acc[4][4] = {};
  for (int k0 = 0; k0 < K; k0 += 8) {
#pragma unroll
    for (int e = t; e < 512; e += 256) {
      int r = e >> 3, kk = e & 7;
      As[kk][r] = X[(size_t)(m0 + r) * K + k0 + kk];
      Bs[kk][r] = W[(size_t)(n0 + r) * K + k0 + kk];
    }
    __syncthreads();
#pragma unroll
    for (int kk = 0; kk < 8; kk++) {
      float4 a4 = *(const float4*)&As[kk][ty * 4];
      float4 b4 = *(const float4*)&Bs[kk][tx * 4];
      float a[4] = {a4.x, a4.y, a4.z, a4.w};
      float b[4] = {b4.x, b4.y, b4.z, b4.w};
#pragma unroll
      for (int i = 0; i < 4; i++)
#pragma unroll
        for (int j = 0; j < 4; j++) acc[i][j] += a[i] * b[j];
    }
    __syncthreads();
  }
#pragma unroll
  for (int i = 0; i < 4; i++) {
    int m = m0 + ty * 4 + i;
#pragma unroll
    for (int j = 0; j < 4; j++) {
      int n = n0 + tx * 4 + j;
      float v = acc[i][j] + bias[n];
      if (res) v += res[(size_t)m * Nc + n];
      if (act) v = 0.5f * v * (1.0f + erff(v * 0.70710678118f));
      C[(size_t)m * Nc + n] = v;
    }
  }
}

// ---------------- attention: block = (32 q-rows, one head, one batch) ----------------
// 256 threads = 32 q-rows x 8 key-slots; per-thread online softmax over its 256 keys,
// 8-slot merge in LDS at the end. qkv layout: [B*N, 3, H, 16].
__global__ __launch_bounds__(256) void attn_kernel(
    const float* __restrict__ qkv, const float* __restrict__ adj,
    const int* __restrict__ mask, const float* __restrict__ sbias, int layer,
    float* __restrict__ o) {
  int b = blockIdx.z, hh = blockIdx.y, q0 = blockIdx.x * 32;
  int t = threadIdx.x;
  int tq = t & 31, slot = t >> 5;
  int q = q0 + tq;
  int rowq = b * NN + q;
  float sb = sbias[layer];
  int mq = mask[rowq];
  const float* qp = qkv + (size_t)rowq * 384 + hh * NDH;
  float4 qv[4];
#pragma unroll
  for (int s = 0; s < 4; s++) qv[s] = *(const float4*)&qp[s * 4];
  float mloc = -INFINITY, l = 0.f;
  float o0[16];
#pragma unroll
  for (int d = 0; d < 16; d++) o0[d] = 0.f;
  const float* adjrow = adj + (size_t)rowq * NN;
  for (int it = 0; it < 64; it++) {
    int j0 = slot * 256 + it * 4;
    float4 a4 = *(const float4*)&adjrow[j0];
    float aa[4] = {a4.x, a4.y, a4.z, a4.w};
#pragma unroll
    for (int c = 0; c < 4; c++) {
      int j = j0 + c;
      int rowk = b * NN + j;
      const float* kp = qkv + (size_t)rowk * 384 + ND + hh * NDH;
      float dot = 0.f;
#pragma unroll
      for (int s = 0; s < 4; s++) {
        float4 k4 = *(const float4*)&kp[s * 4];
        dot += qv[s].x * k4.x + qv[s].y * k4.y + qv[s].z * k4.z + qv[s].w * k4.w;
      }
      int okj = mq ? mask[rowk] : (j == q);
      float sc = dot * ATT_SCALE + sb * aa[c] + (okj ? 0.f : NEGV);
      if (sc > mloc) {
        float cfac = __expf(mloc - sc);
        l *= cfac;
#pragma unroll
        for (int d = 0; d < 16; d++) o0[d] *= cfac;
        mloc = sc;
      }
      float e = __expf(sc - mloc);
      l += e;
      const float* vp = qkv + (size_t)rowk * 384 + 2 * ND + hh * NDH;
#pragma unroll
      for (int s = 0; s < 4; s++) {
        float4 v4 = *(const float4*)&vp[s * 4];
        o0[s * 4 + 0] += e * v4.x;
        o0[s * 4 + 1] += e * v4.y;
        o0[s * 4 + 2] += e * v4.z;
        o0[s * 4 + 3] += e * v4.w;
      }
    }
  }
  __shared__ float Lm[8][32];
  __shared__ float Ll[8][32];
  __shared__ float Lo[8][32][16];
  Lm[slot][tq] = mloc;
  Ll[slot][tq] = l;
#pragma unroll
  for (int d = 0; d < 16; d++) Lo[slot][tq][d] = o0[d];
  __syncthreads();
  if (t < 32) {
    float M = -INFINITY;
#pragma unroll
    for (int s = 0; s < 8; s++) M = fmaxf(M, Lm[s][t]);
    float L = 0.f;
    float w[8];
#pragma unroll
    for (int s = 0; s < 8; s++) {
      w[s] = __expf(Lm[s][t] - M);
      L += Ll[s][t] * w[s];
    }
    float rl = 1.0f / L;
    float* op = o + (size_t)(b * NN + q0 + t) * ND + hh * NDH;
#pragma unroll
    for (int seg = 0; seg < 4; seg++) {
      float acc[4] = {0.f, 0.f, 0.f, 0.f};
#pragma unroll
      for (int s = 0; s < 8; s++)
#pragma unroll
        for (int c = 0; c < 4; c++) acc[c] += Lo[s][t][seg * 4 + c] * w[s];
      float4 r;
      r.x = acc[0] * rl; r.y = acc[1] * rl; r.z = acc[2] * rl; r.w = acc[3] * rl;
      *(float4*)&op[seg * 4] = r;
    }
  }
}

// ---------------- head: pool root row, LN, dot with head_w ----------------
__global__ void head_kernel(const float* __restrict__ h, const int* __restrict__ root_idx,
                            const float* __restrict__ g, const float* __restrict__ bt,
                            const float* __restrict__ hw, const float* __restrict__ hb,
                            float* __restrict__ out) {
  int b = blockIdx.x, lane = threadIdx.x;  // 64 threads
  const float* row = h + ((size_t)b * NN + root_idx[b]) * ND;
  float2 v = *(const float2*)&row[lane * 2];
  float s1 = v.x + v.y, s2 = v.x * v.x + v.y * v.y;
#pragma unroll
  for (int m = 32; m >= 1; m >>= 1) {
    s1 += __shfl_xor(s1, m, 64);
    s2 += __shfl_xor(s2, m, 64);
  }
  float mean = s1 * (1.0f / ND);
  float var = s2 * (1.0f / ND) - mean * mean;
  float rstd = rsqrtf(var + LN_EPS);
  float p0 = (v.x - mean) * rstd * g[lane * 2] + bt[lane * 2];
  float p1 = (v.y - mean) * rstd * g[lane * 2 + 1] + bt[lane * 2 + 1];
  float part = p0 * hw[lane * 2] + p1 * hw[lane * 2 + 1];
#pragma unroll
  for (int m = 32; m >= 1; m >>= 1) part += __shfl_xor(part, m, 64);
  if (lane == 0) out[b] = part + hb[0];
}

extern "C" void kernel_launch(void* const* d_in, const int* in_sizes, int n_in,
                              void* d_out, int out_size, void* d_ws, size_t ws_size,
                              hipStream_t stream) {
  const float* atom_embed = (const float*)d_in[0];
  const float* cons_embed = (const float*)d_in[1];
  const float* in_w  = (const float*)d_in[2];
  const float* in_b  = (const float*)d_in[3];
  const float* qkv_w = (const float*)d_in[4];
  const float* qkv_b = (const float*)d_in[5];
  const float* out_w = (const float*)d_in[6];
  const float* out_b = (const float*)d_in[7];
  const float* ln1_g = (const float*)d_in[8];
  const float* ln1_b = (const float*)d_in[9];
  const float* ln2_g = (const float*)d_in[10];
  const float* ln2_b = (const float*)d_in[11];
  const float* ff1_w = (const float*)d_in[12];
  const float* ff1_b = (const float*)d_in[13];
  const float* ff2_w = (const float*)d_in[14];
  const float* ff2_b = (const float*)d_in[15];
  const float* sbias = (const float*)d_in[16];
  const float* hg    = (const float*)d_in[17];
  const float* hbt   = (const float*)d_in[18];
  const float* hw    = (const float*)d_in[19];
  const float* hb    = (const float*)d_in[20];
  const float* adj   = (const float*)d_in[21];
  const int* is_atom = (const int*)d_in[22];
  const int* atom_id = (const int*)d_in[23];
  const int* mask    = (const int*)d_in[24];
  const int* root_idx= (const int*)d_in[25];
  float* out = (float*)d_out;

  const int MR = NB * NN;  // 4096 rows
  float* ws  = (float*)d_ws;
  float* h   = ws;                 // 4096*128
  float* x   = h + MR * ND;        // 4096*128
  float* qkv = x + MR * ND;        // 4096*384
  float* o   = qkv + MR * 384;     // 4096*128
  float* f   = o + MR * ND;        // 4096*512

  embed_kernel<<<MR * ND / 256, 256, 0, stream>>>(atom_embed, cons_embed, is_atom, atom_id, x);
  dim3 g128(ND / 64, MR / 64), g384(384 / 64, MR / 64), g512(512 / 64, MR / 64);
  sgemm_kernel<<<g128, 256, 0, stream>>>(x, in_w, in_b, nullptr, h, MR, ND, ND, 0);

  for (int i = 0; i < NL; i++) {
    ln_kernel<<<MR / 4, 256, 0, stream>>>(h, x, ln1_g + i * ND, ln1_b + i * ND);
    sgemm_kernel<<<g384, 256, 0, stream>>>(x, qkv_w + i * 384 * ND, qkv_b + i * 384,
                                           nullptr, qkv, MR, 384, ND, 0);
    attn_kernel<<<dim3(NN / 32, NH, NB), 256, 0, stream>>>(qkv, adj, mask, sbias, i, o);
    sgemm_kernel<<<g128, 256, 0, stream>>>(o, out_w + i * ND * ND, out_b + i * ND,
                                           h, h, MR, ND, ND, 0);
    ln_kernel<<<MR / 4, 256, 0, stream>>>(h, x, ln2_g + i * ND, ln2_b + i * ND);
    sgemm_kernel<<<g512, 256, 0, stream>>>(x, ff1_w + i * 512 * ND, ff1_b + i * 512,
                                           nullptr, f, MR, 512, ND, 1);
    sgemm_kernel<<<g128, 256, 0, stream>>>(f, ff2_w + i * ND * 512, ff2_b + i * ND,
                                           h, h, MR, ND, 512, 0);
  }
  head_kernel<<<NB, 64, 0, stream>>>(h, root_idx, hg, hbt, hw, hb, out);
}

// Round 2
// 659.391 us; speedup vs baseline: 1.9412x; 1.9412x over previous
//
#include <hip/hip_runtime.h>
#include <cmath>

#define NB 2
#define NN 2048
#define ND 128
#define NH 8
#define NL 3
#define NV 32
#define NDH 16
#define ATT_SCALE 0.25f  /* 1/sqrt(16) */
#define LN_EPS 1e-5f

typedef __bf16 bf8_t __attribute__((ext_vector_type(8)));
typedef float f4x __attribute__((ext_vector_type(4)));

// ---------------- embedding select ----------------
__global__ void embed_kernel(const float* __restrict__ atom_embed,
                             const float* __restrict__ cons_embed,
                             const int* __restrict__ is_atom,
                             const int* __restrict__ atom_id,
                             float* __restrict__ x) {
  int idx = blockIdx.x * 256 + threadIdx.x;       // over 4096*128
  int row = idx >> 7, d = idx & 127;
  int id = atom_id[row];
  id = id < 0 ? 0 : (id > NV - 1 ? NV - 1 : id);
  float e = is_atom[row] ? atom_embed[id * ND + d] : cons_embed[d];
  x[idx] = e;
}

// ---------------- layernorm over D=128, one wave per row ----------------
__global__ __launch_bounds__(256) void ln_kernel(const float* __restrict__ in,
                                                 float* __restrict__ out,
                                                 const float* __restrict__ g,
                                                 const float* __restrict__ bt) {
  int row = blockIdx.x * 4 + (threadIdx.x >> 6);
  int lane = threadIdx.x & 63;
  const float* xr = in + (size_t)row * ND;
  float2 v = *(const float2*)&xr[lane * 2];
  float s1 = v.x + v.y;
  float s2 = v.x * v.x + v.y * v.y;
#pragma unroll
  for (int m = 32; m >= 1; m >>= 1) {
    s1 += __shfl_xor(s1, m, 64);
    s2 += __shfl_xor(s2, m, 64);
  }
  float mean = s1 * (1.0f / ND);
  float var = s2 * (1.0f / ND) - mean * mean;
  float rstd = rsqrtf(var + LN_EPS);
  float2 gg = *(const float2*)&g[lane * 2];
  float2 bb = *(const float2*)&bt[lane * 2];
  float2 o;
  o.x = (v.x - mean) * rstd * gg.x + bb.x;
  o.y = (v.y - mean) * rstd * gg.y + bb.y;
  *(float2*)&out[(size_t)row * ND + lane * 2] = o;
}

// ---------------- fp32 SGEMM: C[M,Nc] = X[M,K] @ W[Nc,K]^T + bias (+res)(gelu) ----------------
__global__ __launch_bounds__(256) void sgemm_kernel(
    const float* __restrict__ X, const float* __restrict__ W,
    const float* __restrict__ bias, const float* __restrict__ res,
    float* __restrict__ C, int M, int Nc, int K, int act) {
  __shared__ float As[8][64];
  __shared__ float Bs[8][64];
  int m0 = blockIdx.y * 64, n0 = blockIdx.x * 64;
  int t = threadIdx.x, tx = t & 15, ty = t >> 4;
  float acc[4][4] = {};
  for (int k0 = 0; k0 < K; k0 += 8) {
#pragma unroll
    for (int e = t; e < 512; e += 256) {
      int r = e >> 3, kk = e & 7;
      As[kk][r] = X[(size_t)(m0 + r) * K + k0 + kk];
      Bs[kk][r] = W[(size_t)(n0 + r) * K + k0 + kk];
    }
    __syncthreads();
#pragma unroll
    for (int kk = 0; kk < 8; kk++) {
      float4 a4 = *(const float4*)&As[kk][ty * 4];
      float4 b4 = *(const float4*)&Bs[kk][tx * 4];
      float a[4] = {a4.x, a4.y, a4.z, a4.w};
      float b[4] = {b4.x, b4.y, b4.z, b4.w};
#pragma unroll
      for (int i = 0; i < 4; i++)
#pragma unroll
        for (int j = 0; j < 4; j++) acc[i][j] += a[i] * b[j];
    }
    __syncthreads();
  }
#pragma unroll
  for (int i = 0; i < 4; i++) {
    int m = m0 + ty * 4 + i;
#pragma unroll
    for (int j = 0; j < 4; j++) {
      int n = n0 + tx * 4 + j;
      float v = acc[i][j] + bias[n];
      if (res) v += res[(size_t)m * Nc + n];
      if (act) v = 0.5f * v * (1.0f + erff(v * 0.70710678118f));
      C[(size_t)m * Nc + n] = v;
    }
  }
}

// ---------------- MFMA flash attention (no-max softmax, key-split across waves) ----
// Block: 16 q-rows x 1 head. 4 waves each handle a 512-key partition (16 tiles
// of 32 keys). QK^T: two mfma_f32_16x16x32_bf16 (DH=16 zero-padded to K=32,
// verified fragment layouts only). P -> LDS -> A-layout, PV: one K=32 MFMA.
// Scores are bounded (|dot|*0.25 <~ 0.5, |sb*adj| <~ 2.5) so exp() without max
// subtraction is numerically safe; masked entries contribute exactly 0. Partial
// (O, l) combine linearly across waves in LDS.
__global__ __launch_bounds__(256) void attn_kernel(
    const float* __restrict__ qkv, const float* __restrict__ adj,
    const int* __restrict__ mask, const float* __restrict__ sbias, int layer,
    float* __restrict__ o) {
  int b = blockIdx.z, hh = blockIdx.y, q0 = blockIdx.x * 16;
  int wave = threadIdx.x >> 6;
  int lane = threadIdx.x & 63;
  int l15 = lane & 15, quad = lane >> 4;
  float sb = sbias[layer];
  const int bN = b * NN;

  __shared__ __bf16 Pbuf[4][16][40];   // row stride 40 shorts = 80B (16B-aligned rows)
  __shared__ float Ored[4][16][17];
  __shared__ float Lred[4][16];

  // Q A-fragment: A[m=lane&15][k=quad*8+j]; real dh = k for k<16, zero-pad above.
  bf8_t Af;
  if (quad < 2) {
    const float* qp = qkv + (size_t)(bN + q0 + l15) * 384 + hh * NDH + quad * 8;
    float4 x0 = *(const float4*)qp;
    float4 x1 = *(const float4*)(qp + 4);
    Af[0] = (__bf16)x0.x; Af[1] = (__bf16)x0.y; Af[2] = (__bf16)x0.z; Af[3] = (__bf16)x0.w;
    Af[4] = (__bf16)x1.x; Af[5] = (__bf16)x1.y; Af[6] = (__bf16)x1.z; Af[7] = (__bf16)x1.w;
  } else {
#pragma unroll
    for (int j = 0; j < 8; j++) Af[j] = (__bf16)0.f;
  }

  int qrow[4], mq[4];
#pragma unroll
  for (int r = 0; r < 4; r++) {
    qrow[r] = q0 + quad * 4 + r;
    mq[r] = mask[bN + qrow[r]];
  }

  f4x O = {0.f, 0.f, 0.f, 0.f};
  float ls[4] = {0.f, 0.f, 0.f, 0.f};

  for (int t = 0; t < 16; t++) {
    int kb = wave * 512 + t * 32;
    f4x S[2];
#pragma unroll
    for (int s = 0; s < 2; s++) {
      bf8_t Kf;
      if (quad < 2) {
        const float* kp = qkv + (size_t)(bN + kb + s * 16 + l15) * 384 + ND + hh * NDH + quad * 8;
        float4 x0 = *(const float4*)kp;
        float4 x1 = *(const float4*)(kp + 4);
        Kf[0] = (__bf16)x0.x; Kf[1] = (__bf16)x0.y; Kf[2] = (__bf16)x0.z; Kf[3] = (__bf16)x0.w;
        Kf[4] = (__bf16)x1.x; Kf[5] = (__bf16)x1.y; Kf[6] = (__bf16)x1.z; Kf[7] = (__bf16)x1.w;
      } else {
#pragma unroll
        for (int j = 0; j < 8; j++) Kf[j] = (__bf16)0.f;
      }
      f4x z = {0.f, 0.f, 0.f, 0.f};
      S[s] = __builtin_amdgcn_mfma_f32_16x16x32_bf16(Af, Kf, z, 0, 0, 0);
    }
    int mj[2];
    mj[0] = mask[bN + kb + l15];
    mj[1] = mask[bN + kb + 16 + l15];
#pragma unroll
    for (int s = 0; s < 2; s++) {
      int j = kb + s * 16 + l15;
#pragma unroll
      for (int r = 0; r < 4; r++) {
        float av = adj[(size_t)(bN + qrow[r]) * NN + j];
        bool ok = mq[r] ? (mj[s] != 0) : (j == qrow[r]);
        float p = ok ? __expf(S[s][r] * ATT_SCALE + sb * av) : 0.f;
        ls[r] += p;
        Pbuf[wave][quad * 4 + r][s * 16 + l15] = (__bf16)p;
      }
    }
    // wave-private LDS write->read; drain lgkm before reading back
    asm volatile("s_waitcnt lgkmcnt(0)" ::: "memory");
    bf8_t Pf = *(const bf8_t*)&Pbuf[wave][l15][quad * 8];
    bf8_t Vf;
#pragma unroll
    for (int j = 0; j < 8; j++) {
      Vf[j] = (__bf16)qkv[(size_t)(bN + kb + quad * 8 + j) * 384 + 2 * ND + hh * NDH + l15];
    }
    O = __builtin_amdgcn_mfma_f32_16x16x32_bf16(Pf, Vf, O, 0, 0, 0);
  }

#pragma unroll
  for (int r = 0; r < 4; r++) {
    float v = ls[r];
    v += __shfl_xor(v, 1, 64);
    v += __shfl_xor(v, 2, 64);
    v += __shfl_xor(v, 4, 64);
    v += __shfl_xor(v, 8, 64);
    if (l15 == 0) Lred[wave][quad * 4 + r] = v;
    Ored[wave][quad * 4 + r][l15] = O[r];
  }
  __syncthreads();
  int row = threadIdx.x >> 4, col = threadIdx.x & 15;
  float s = Ored[0][row][col] + Ored[1][row][col] + Ored[2][row][col] + Ored[3][row][col];
  float L = Lred[0][row] + Lred[1][row] + Lred[2][row] + Lred[3][row];
  o[(size_t)(bN + q0 + row) * ND + hh * NDH + col] = s / L;
}

// ---------------- head: pool root row, LN, dot with head_w ----------------
__global__ void head_kernel(const float* __restrict__ h, const int* __restrict__ root_idx,
                            const float* __restrict__ g, const float* __restrict__ bt,
                            const float* __restrict__ hw, const float* __restrict__ hb,
                            float* __restrict__ out) {
  int b = blockIdx.x, lane = threadIdx.x;  // 64 threads
  const float* row = h + ((size_t)b * NN + root_idx[b]) * ND;
  float2 v = *(const float2*)&row[lane * 2];
  float s1 = v.x + v.y, s2 = v.x * v.x + v.y * v.y;
#pragma unroll
  for (int m = 32; m >= 1; m >>= 1) {
    s1 += __shfl_xor(s1, m, 64);
    s2 += __shfl_xor(s2, m, 64);
  }
  float mean = s1 * (1.0f / ND);
  float var = s2 * (1.0f / ND) - mean * mean;
  float rstd = rsqrtf(var + LN_EPS);
  float p0 = (v.x - mean) * rstd * g[lane * 2] + bt[lane * 2];
  float p1 = (v.y - mean) * rstd * g[lane * 2 + 1] + bt[lane * 2 + 1];
  float part = p0 * hw[lane * 2] + p1 * hw[lane * 2 + 1];
#pragma unroll
  for (int m = 32; m >= 1; m >>= 1) part += __shfl_xor(part, m, 64);
  if (lane == 0) out[b] = part + hb[0];
}

extern "C" void kernel_launch(void* const* d_in, const int* in_sizes, int n_in,
                              void* d_out, int out_size, void* d_ws, size_t ws_size,
                              hipStream_t stream) {
  const float* atom_embed = (const float*)d_in[0];
  const float* cons_embed = (const float*)d_in[1];
  const float* in_w  = (const float*)d_in[2];
  const float* in_b  = (const float*)d_in[3];
  const float* qkv_w = (const float*)d_in[4];
  const float* qkv_b = (const float*)d_in[5];
  const float* out_w = (const float*)d_in[6];
  const float* out_b = (const float*)d_in[7];
  const float* ln1_g = (const float*)d_in[8];
  const float* ln1_b = (const float*)d_in[9];
  const float* ln2_g = (const float*)d_in[10];
  const float* ln2_b = (const float*)d_in[11];
  const float* ff1_w = (const float*)d_in[12];
  const float* ff1_b = (const float*)d_in[13];
  const float* ff2_w = (const float*)d_in[14];
  const float* ff2_b = (const float*)d_in[15];
  const float* sbias = (const float*)d_in[16];
  const float* hg    = (const float*)d_in[17];
  const float* hbt   = (const float*)d_in[18];
  const float* hw    = (const float*)d_in[19];
  const float* hb    = (const float*)d_in[20];
  const float* adj   = (const float*)d_in[21];
  const int* is_atom = (const int*)d_in[22];
  const int* atom_id = (const int*)d_in[23];
  const int* mask    = (const int*)d_in[24];
  const int* root_idx= (const int*)d_in[25];
  float* out = (float*)d_out;

  const int MR = NB * NN;  // 4096 rows
  float* ws  = (float*)d_ws;
  float* h   = ws;                 // 4096*128
  float* x   = h + MR * ND;        // 4096*128
  float* qkv = x + MR * ND;        // 4096*384
  float* o   = qkv + MR * 384;     // 4096*128
  float* f   = o + MR * ND;        // 4096*512

  embed_kernel<<<MR * ND / 256, 256, 0, stream>>>(atom_embed, cons_embed, is_atom, atom_id, x);
  dim3 g128(ND / 64, MR / 64), g384(384 / 64, MR / 64), g512(512 / 64, MR / 64);
  sgemm_kernel<<<g128, 256, 0, stream>>>(x, in_w, in_b, nullptr, h, MR, ND, ND, 0);

  for (int i = 0; i < NL; i++) {
    ln_kernel<<<MR / 4, 256, 0, stream>>>(h, x, ln1_g + i * ND, ln1_b + i * ND);
    sgemm_kernel<<<g384, 256, 0, stream>>>(x, qkv_w + i * 384 * ND, qkv_b + i * 384,
                                           nullptr, qkv, MR, 384, ND, 0);
    attn_kernel<<<dim3(NN / 16, NH, NB), 256, 0, stream>>>(qkv, adj, mask, sbias, i, o);
    sgemm_kernel<<<g128, 256, 0, stream>>>(o, out_w + i * ND * ND, out_b + i * ND,
                                           h, h, MR, ND, ND, 0);
    ln_kernel<<<MR / 4, 256, 0, stream>>>(h, x, ln2_g + i * ND, ln2_b + i * ND);
    sgemm_kernel<<<g512, 256, 0, stream>>>(x, ff1_w + i * 512 * ND, ff1_b + i * 512,
                                           nullptr, f, MR, 512, ND, 1);
    sgemm_kernel<<<g128, 256, 0, stream>>>(f, ff2_w + i * ND * 512, ff2_b + i * ND,
                                           h, h, MR, ND, 512, 0);
  }
  head_kernel<<<NB, 64, 0, stream>>>(h, root_idx, hg, hbt, hw, hb, out);
}

// Round 3
// 488.135 us; speedup vs baseline: 2.6222x; 1.3508x over previous
//
#include <hip/hip_runtime.h>
#include <cmath>

#define NB 2
#define NN 2048
#define ND 128
#define NH 8
#define NL 3
#define NV 32
#define NDH 16
#define ATT_SCALE 0.25f  /* 1/sqrt(16) */
#define LN_EPS 1e-5f

typedef __bf16 bf8_t __attribute__((ext_vector_type(8)));
typedef __bf16 bf4_t __attribute__((ext_vector_type(4)));
typedef float f4x __attribute__((ext_vector_type(4)));

// ---------------- embedding select ----------------
__global__ void embed_kernel(const float* __restrict__ atom_embed,
                             const float* __restrict__ cons_embed,
                             const int* __restrict__ is_atom,
                             const int* __restrict__ atom_id,
                             float* __restrict__ x) {
  int idx = blockIdx.x * 256 + threadIdx.x;       // over 4096*128
  int row = idx >> 7, d = idx & 127;
  int id = atom_id[row];
  id = id < 0 ? 0 : (id > NV - 1 ? NV - 1 : id);
  float e = is_atom[row] ? atom_embed[id * ND + d] : cons_embed[d];
  x[idx] = e;
}

// ---------------- bit-pack adjacency (values are exactly 0/1) ----------------
__global__ __launch_bounds__(256) void adjbits_kernel(const float* __restrict__ adj,
                                                      unsigned long long* __restrict__ bits) {
  int g = blockIdx.x * 4 + (threadIdx.x >> 6);
  int lane = threadIdx.x & 63;
  float v = adj[(size_t)g * 64 + lane];
  unsigned long long bal = __ballot(v != 0.0f);
  if (lane == 0) bits[g] = bal;
}

__global__ void maskbits_kernel(const int* __restrict__ mask,
                                unsigned long long* __restrict__ bits) {
  int g = blockIdx.x * 4 + (threadIdx.x >> 6);   // 16 blocks x 4 waves = 64 groups
  int lane = threadIdx.x & 63;
  int v = mask[g * 64 + lane];
  unsigned long long bal = __ballot(v != 0);
  if (lane == 0) bits[g] = bal;
}

// ---------------- layernorm over D=128, one wave per row ----------------
__global__ __launch_bounds__(256) void ln_kernel(const float* __restrict__ in,
                                                 float* __restrict__ out,
                                                 const float* __restrict__ g,
                                                 const float* __restrict__ bt) {
  int row = blockIdx.x * 4 + (threadIdx.x >> 6);
  int lane = threadIdx.x & 63;
  const float* xr = in + (size_t)row * ND;
  float2 v = *(const float2*)&xr[lane * 2];
  float s1 = v.x + v.y;
  float s2 = v.x * v.x + v.y * v.y;
#pragma unroll
  for (int m = 32; m >= 1; m >>= 1) {
    s1 += __shfl_xor(s1, m, 64);
    s2 += __shfl_xor(s2, m, 64);
  }
  float mean = s1 * (1.0f / ND);
  float var = s2 * (1.0f / ND) - mean * mean;
  float rstd = rsqrtf(var + LN_EPS);
  float2 gg = *(const float2*)&g[lane * 2];
  float2 bb = *(const float2*)&bt[lane * 2];
  float2 o;
  o.x = (v.x - mean) * rstd * gg.x + bb.x;
  o.y = (v.y - mean) * rstd * gg.y + bb.y;
  *(float2*)&out[(size_t)row * ND + lane * 2] = o;
}

// ---------------- fp32 SGEMM v2: float4-staged LDS, BK=16 ----------------
// C[M,Nc] = X[M,K] @ W[Nc,K]^T + bias; mode 0: plain (+res), 1: gelu, 2: qkv->bf16 pack.
// MT in {32,64}; NT=64; 256 threads.
template <int MT>
__global__ __launch_bounds__(256) void sgemm2_kernel(
    const float* __restrict__ X, const float* __restrict__ W,
    const float* __restrict__ bias, const float* __restrict__ res,
    float* __restrict__ C, __bf16* __restrict__ Qb, __bf16* __restrict__ Kb,
    __bf16* __restrict__ Vt, int M, int Nc, int K, int mode) {
  constexpr int APAD = MT + 4;
  __shared__ float As[16][APAD];
  __shared__ float Bs[16][68];
  int m0 = blockIdx.y * MT, n0 = blockIdx.x * 64;
  int t = threadIdx.x, tx = t & 15, ty = t >> 4;
  constexpr int RPT = MT / 16;          // rows per thread (2 or 4)
  float acc[RPT][4] = {};
  int xrow = t >> 2, kc = t & 3;
  for (int k0 = 0; k0 < K; k0 += 16) {
    if (MT == 64 || t < 128) {
      float4 g = *(const float4*)&X[(size_t)(m0 + xrow) * K + k0 + kc * 4];
      As[kc * 4 + 0][xrow] = g.x; As[kc * 4 + 1][xrow] = g.y;
      As[kc * 4 + 2][xrow] = g.z; As[kc * 4 + 3][xrow] = g.w;
    }
    {
      float4 g = *(const float4*)&W[(size_t)(n0 + xrow) * K + k0 + kc * 4];
      Bs[kc * 4 + 0][xrow] = g.x; Bs[kc * 4 + 1][xrow] = g.y;
      Bs[kc * 4 + 2][xrow] = g.z; Bs[kc * 4 + 3][xrow] = g.w;
    }
    __syncthreads();
#pragma unroll
    for (int kk = 0; kk < 16; kk++) {
      float4 b4 = *(const float4*)&Bs[kk][tx * 4];
      float bv[4] = {b4.x, b4.y, b4.z, b4.w};
      float av[RPT];
      if (MT == 64) {
        float4 a4 = *(const float4*)&As[kk][ty * 4];
        av[0] = a4.x; av[1] = a4.y; av[2] = a4.z; av[3] = a4.w;
      } else {
        float2 a2 = *(const float2*)&As[kk][ty * 2];
        av[0] = a2.x; av[1] = a2.y;
      }
#pragma unroll
      for (int i = 0; i < RPT; i++)
#pragma unroll
        for (int j = 0; j < 4; j++) acc[i][j] += av[i] * bv[j];
    }
    __syncthreads();
  }
#pragma unroll
  for (int i = 0; i < RPT; i++) {
    int m = m0 + ty * RPT + i;
    int n = n0 + tx * 4;
    float v[4];
#pragma unroll
    for (int j = 0; j < 4; j++) v[j] = acc[i][j] + bias[n + j];
    if (mode == 2) {
      if (n < 2 * ND) {
        bf4_t p;
#pragma unroll
        for (int j = 0; j < 4; j++) p[j] = (__bf16)v[j];
        if (n < ND) *(bf4_t*)&Qb[(size_t)m * ND + n] = p;
        else        *(bf4_t*)&Kb[(size_t)m * ND + n - ND] = p;
      } else {
        int c = n - 2 * ND, hh = c >> 4, d0 = c & 15;
        int bb = m >> 11, nn = m & 2047;
#pragma unroll
        for (int j = 0; j < 4; j++)
          Vt[((size_t)((bb * NH + hh) * NDH + d0 + j)) * NN + nn] = (__bf16)v[j];
      }
    } else {
      if (res) {
        float4 r4 = *(const float4*)&res[(size_t)m * Nc + n];
        v[0] += r4.x; v[1] += r4.y; v[2] += r4.z; v[3] += r4.w;
      }
      if (mode == 1) {
#pragma unroll
        for (int j = 0; j < 4; j++)
          v[j] = 0.5f * v[j] * (1.0f + erff(v[j] * 0.70710678118f));
      }
      float4 o4 = {v[0], v[1], v[2], v[3]};
      *(float4*)&C[(size_t)m * Nc + n] = o4;
    }
  }
}

// ---------------- MFMA flash attention v2 ----------------
// Block: 16 q-rows x 1 head; 4 waves each own a 512-key partition (16 tiles of
// 32 keys). No-max softmax (scores bounded). Bit-packed adjacency/mask; bf16
// prepacked Kb [row][h][16] and Vt [b][h][dh][N] give 16B fragment loads.
__global__ __launch_bounds__(256) void attn_kernel(
    const __bf16* __restrict__ Qb, const __bf16* __restrict__ Kb,
    const __bf16* __restrict__ Vt, const unsigned int* __restrict__ adjbits,
    const unsigned int* __restrict__ maskbits, const int* __restrict__ mask,
    const float* __restrict__ sbias, int layer, float* __restrict__ o) {
  int b = blockIdx.z, hh = blockIdx.y, q0 = blockIdx.x * 16;
  int wave = threadIdx.x >> 6;
  int lane = threadIdx.x & 63;
  int l15 = lane & 15, quad = lane >> 4;
  float sb = sbias[layer];
  float esb = __expf(sb);
  const int bN = b * NN;
  const int kw0 = wave * 512;

  __shared__ __bf16 Pbuf[4][16][40];
  __shared__ float Ored[4][16][17];
  __shared__ float Lred[4][16];

  bf8_t Af;
  if (quad < 2) {
    Af = *(const bf8_t*)(Qb + (size_t)(bN + q0 + l15) * ND + hh * NDH + quad * 8);
  } else {
#pragma unroll
    for (int j = 0; j < 8; j++) Af[j] = (__bf16)0.f;
  }

  int qrow[4], mq[4];
  const unsigned int* adjp[4];
#pragma unroll
  for (int r = 0; r < 4; r++) {
    qrow[r] = q0 + quad * 4 + r;
    mq[r] = mask[bN + qrow[r]];
    adjp[r] = adjbits + (size_t)(bN + qrow[r]) * (NN / 32) + (kw0 >> 5);
  }
  const unsigned int* mbp = maskbits + (bN + kw0) / 32;
  const __bf16* kp = Kb + (size_t)(bN + kw0 + l15) * ND + hh * NDH + quad * 8;
  const __bf16* vp = Vt + (size_t)((b * NH + hh) * NDH + l15) * NN + kw0 + quad * 8;

  f4x O = {0.f, 0.f, 0.f, 0.f};
  float ls[4] = {0.f, 0.f, 0.f, 0.f};

  for (int t = 0; t < 16; t++) {
    bf8_t K0, K1;
    if (quad < 2) {
      K0 = *(const bf8_t*)kp;
      K1 = *(const bf8_t*)(kp + 16 * ND);
    } else {
#pragma unroll
      for (int j = 0; j < 8; j++) { K0[j] = (__bf16)0.f; K1[j] = (__bf16)0.f; }
    }
    bf8_t Vf = *(const bf8_t*)(vp + t * 32);
    f4x z = {0.f, 0.f, 0.f, 0.f};
    f4x S0 = __builtin_amdgcn_mfma_f32_16x16x32_bf16(Af, K0, z, 0, 0, 0);
    f4x S1 = __builtin_amdgcn_mfma_f32_16x16x32_bf16(Af, K1, z, 0, 0, 0);
    unsigned int mkw = mbp[t];
    unsigned int aw[4] = {adjp[0][t], adjp[1][t], adjp[2][t], adjp[3][t]};
    int kb = bN + kw0 + t * 32;
#pragma unroll
    for (int s = 0; s < 2; s++) {
      int bitpos = s * 16 + l15;
      int j = kb + bitpos - bN;            // key index within batch
      int mj = (mkw >> bitpos) & 1;
      const f4x& S = s ? S1 : S0;
#pragma unroll
      for (int r = 0; r < 4; r++) {
        float e = __expf(S[r] * ATT_SCALE);
        float f = ((aw[r] >> bitpos) & 1) ? esb : 1.0f;
        bool ok = mq[r] ? (mj != 0) : (j == qrow[r]);
        float p = ok ? e * f : 0.f;
        ls[r] += p;
        Pbuf[wave][quad * 4 + r][bitpos] = (__bf16)p;
      }
    }
    // wave-private LDS write->read; drain lgkm before reading back
    asm volatile("s_waitcnt lgkmcnt(0)" ::: "memory");
    bf8_t Pf = *(const bf8_t*)&Pbuf[wave][l15][quad * 8];
    O = __builtin_amdgcn_mfma_f32_16x16x32_bf16(Pf, Vf, O, 0, 0, 0);
    kp += 32 * ND;
  }

#pragma unroll
  for (int r = 0; r < 4; r++) {
    float v = ls[r];
    v += __shfl_xor(v, 1, 64);
    v += __shfl_xor(v, 2, 64);
    v += __shfl_xor(v, 4, 64);
    v += __shfl_xor(v, 8, 64);
    if (l15 == 0) Lred[wave][quad * 4 + r] = v;
    Ored[wave][quad * 4 + r][l15] = O[r];
  }
  __syncthreads();
  int row = threadIdx.x >> 4, col = threadIdx.x & 15;
  float s = Ored[0][row][col] + Ored[1][row][col] + Ored[2][row][col] + Ored[3][row][col];
  float L = Lred[0][row] + Lred[1][row] + Lred[2][row] + Lred[3][row];
  o[(size_t)(bN + q0 + row) * ND + hh * NDH + col] = s / L;
}

// ---------------- head: pool root row, LN, dot with head_w ----------------
__global__ void head_kernel(const float* __restrict__ h, const int* __restrict__ root_idx,
                            const float* __restrict__ g, const float* __restrict__ bt,
                            const float* __restrict__ hw, const float* __restrict__ hb,
                            float* __restrict__ out) {
  int b = blockIdx.x, lane = threadIdx.x;  // 64 threads
  const float* row = h + ((size_t)b * NN + root_idx[b]) * ND;
  float2 v = *(const float2*)&row[lane * 2];
  float s1 = v.x + v.y, s2 = v.x * v.x + v.y * v.y;
#pragma unroll
  for (int m = 32; m >= 1; m >>= 1) {
    s1 += __shfl_xor(s1, m, 64);
    s2 += __shfl_xor(s2, m, 64);
  }
  float mean = s1 * (1.0f / ND);
  float var = s2 * (1.0f / ND) - mean * mean;
  float rstd = rsqrtf(var + LN_EPS);
  float p0 = (v.x - mean) * rstd * g[lane * 2] + bt[lane * 2];
  float p1 = (v.y - mean) * rstd * g[lane * 2 + 1] + bt[lane * 2 + 1];
  float part = p0 * hw[lane * 2] + p1 * hw[lane * 2 + 1];
#pragma unroll
  for (int m = 32; m >= 1; m >>= 1) part += __shfl_xor(part, m, 64);
  if (lane == 0) out[b] = part + hb[0];
}

extern "C" void kernel_launch(void* const* d_in, const int* in_sizes, int n_in,
                              void* d_out, int out_size, void* d_ws, size_t ws_size,
                              hipStream_t stream) {
  const float* atom_embed = (const float*)d_in[0];
  const float* cons_embed = (const float*)d_in[1];
  const float* in_w  = (const float*)d_in[2];
  const float* in_b  = (const float*)d_in[3];
  const float* qkv_w = (const float*)d_in[4];
  const float* qkv_b = (const float*)d_in[5];
  const float* out_w = (const float*)d_in[6];
  const float* out_b = (const float*)d_in[7];
  const float* ln1_g = (const float*)d_in[8];
  const float* ln1_b = (const float*)d_in[9];
  const float* ln2_g = (const float*)d_in[10];
  const float* ln2_b = (const float*)d_in[11];
  const float* ff1_w = (const float*)d_in[12];
  const float* ff1_b = (const float*)d_in[13];
  const float* ff2_w = (const float*)d_in[14];
  const float* ff2_b = (const float*)d_in[15];
  const float* sbias = (const float*)d_in[16];
  const float* hg    = (const float*)d_in[17];
  const float* hbt   = (const float*)d_in[18];
  const float* hw    = (const float*)d_in[19];
  const float* hb    = (const float*)d_in[20];
  const float* adj   = (const float*)d_in[21];
  const int* is_atom = (const int*)d_in[22];
  const int* atom_id = (const int*)d_in[23];
  const int* mask    = (const int*)d_in[24];
  const int* root_idx= (const int*)d_in[25];
  float* out = (float*)d_out;

  const int MR = NB * NN;  // 4096 rows
  float* ws = (float*)d_ws;
  float* h  = ws;                        // 524288
  float* x  = h + MR * ND;               // 524288
  float* o  = x + MR * ND;               // 524288
  float* f  = o + MR * ND;               // 2097152
  __bf16* Qb = (__bf16*)(f + MR * 512);  // 524288 bf16
  __bf16* Kb = Qb + MR * ND;
  __bf16* Vt = Kb + MR * ND;
  unsigned int* adjb = (unsigned int*)(Vt + MR * ND);     // 262144 u32
  unsigned int* mskb = adjb + NB * NN * NN / 32;          // 128 u32

  adjbits_kernel<<<NB * NN * NN / 64 / 4, 256, 0, stream>>>(adj, (unsigned long long*)adjb);
  maskbits_kernel<<<16, 256, 0, stream>>>(mask, (unsigned long long*)mskb);
  embed_kernel<<<MR * ND / 256, 256, 0, stream>>>(atom_embed, cons_embed, is_atom, atom_id, x);
  sgemm2_kernel<32><<<dim3(2, MR / 32), 256, 0, stream>>>(
      x, in_w, in_b, nullptr, h, nullptr, nullptr, nullptr, MR, ND, ND, 0);

  for (int i = 0; i < NL; i++) {
    ln_kernel<<<MR / 4, 256, 0, stream>>>(h, x, ln1_g + i * ND, ln1_b + i * ND);
    sgemm2_kernel<64><<<dim3(6, MR / 64), 256, 0, stream>>>(
        x, qkv_w + i * 384 * ND, qkv_b + i * 384, nullptr, nullptr, Qb, Kb, Vt,
        MR, 384, ND, 2);
    attn_kernel<<<dim3(NN / 16, NH, NB), 256, 0, stream>>>(
        Qb, Kb, Vt, adjb, mskb, mask, sbias, i, o);
    sgemm2_kernel<32><<<dim3(2, MR / 32), 256, 0, stream>>>(
        o, out_w + i * ND * ND, out_b + i * ND, h, h, nullptr, nullptr, nullptr,
        MR, ND, ND, 0);
    ln_kernel<<<MR / 4, 256, 0, stream>>>(h, x, ln2_g + i * ND, ln2_b + i * ND);
    sgemm2_kernel<64><<<dim3(8, MR / 64), 256, 0, stream>>>(
        x, ff1_w + i * 512 * ND, ff1_b + i * 512, nullptr, f, nullptr, nullptr,
        nullptr, MR, 512, ND, 1);
    sgemm2_kernel<32><<<dim3(2, MR / 32), 256, 0, stream>>>(
        f, ff2_w + i * ND * 512, ff2_b + i * ND, h, h, nullptr, nullptr, nullptr,
        MR, ND, 512, 0);
  }
  head_kernel<<<NB, 64, 0, stream>>>(h, root_idx, hg, hbt, hw, hb, out);
}

// Round 4
// 402.147 us; speedup vs baseline: 3.1829x; 1.2138x over previous
//
#include <hip/hip_runtime.h>
#include <cmath>

#define NB 2
#define NN 2048
#define ND 128
#define NH 8
#define NL 3
#define NV 32
#define NDH 16
#define ATT_SCALE 0.25f  /* 1/sqrt(16) */
#define LN_EPS 1e-5f

typedef __bf16 bf8_t __attribute__((ext_vector_type(8)));
typedef __bf16 bf4_t __attribute__((ext_vector_type(4)));
typedef __bf16 bf2_t __attribute__((ext_vector_type(2)));
typedef float f4x __attribute__((ext_vector_type(4)));

// ---------------- fp32 -> bf16 cast (weights, once per launch) ----------------
__global__ void castbf_kernel(const float* __restrict__ src, __bf16* __restrict__ dst, int n4) {
  int i = blockIdx.x * 256 + threadIdx.x;
  if (i < n4) {
    float4 v = ((const float4*)src)[i];
    bf4_t p = {(__bf16)v.x, (__bf16)v.y, (__bf16)v.z, (__bf16)v.w};
    ((bf4_t*)dst)[i] = p;
  }
}

// ---------------- embedding select -> bf16 ----------------
__global__ void embed_kernel(const float* __restrict__ atom_embed,
                             const float* __restrict__ cons_embed,
                             const int* __restrict__ is_atom,
                             const int* __restrict__ atom_id,
                             __bf16* __restrict__ x) {
  int idx = blockIdx.x * 256 + threadIdx.x;       // over 4096*128
  int row = idx >> 7, d = idx & 127;
  int id = atom_id[row];
  id = id < 0 ? 0 : (id > NV - 1 ? NV - 1 : id);
  float e = is_atom[row] ? atom_embed[id * ND + d] : cons_embed[d];
  x[idx] = (__bf16)e;
}

// ---------------- bit-pack adjacency (values are exactly 0/1) ----------------
__global__ __launch_bounds__(256) void adjbits_kernel(const float* __restrict__ adj,
                                                      unsigned long long* __restrict__ bits) {
  int g = blockIdx.x * 4 + (threadIdx.x >> 6);
  int lane = threadIdx.x & 63;
  float v = adj[(size_t)g * 64 + lane];
  unsigned long long bal = __ballot(v != 0.0f);
  if (lane == 0) bits[g] = bal;
}

__global__ void maskbits_kernel(const int* __restrict__ mask,
                                unsigned long long* __restrict__ bits) {
  int g = blockIdx.x * 4 + (threadIdx.x >> 6);
  int lane = threadIdx.x & 63;
  int v = mask[g * 64 + lane];
  unsigned long long bal = __ballot(v != 0);
  if (lane == 0) bits[g] = bal;
}

// ---------------- layernorm over D=128, one wave per row; bf16 out ----------------
__global__ __launch_bounds__(256) void ln_kernel(const float* __restrict__ in,
                                                 __bf16* __restrict__ out,
                                                 const float* __restrict__ g,
                                                 const float* __restrict__ bt) {
  int row = blockIdx.x * 4 + (threadIdx.x >> 6);
  int lane = threadIdx.x & 63;
  const float* xr = in + (size_t)row * ND;
  float2 v = *(const float2*)&xr[lane * 2];
  float s1 = v.x + v.y;
  float s2 = v.x * v.x + v.y * v.y;
#pragma unroll
  for (int m = 32; m >= 1; m >>= 1) {
    s1 += __shfl_xor(s1, m, 64);
    s2 += __shfl_xor(s2, m, 64);
  }
  float mean = s1 * (1.0f / ND);
  float var = s2 * (1.0f / ND) - mean * mean;
  float rstd = rsqrtf(var + LN_EPS);
  float2 gg = *(const float2*)&g[lane * 2];
  float2 bb = *(const float2*)&bt[lane * 2];
  bf2_t o;
  o[0] = (__bf16)((v.x - mean) * rstd * gg.x + bb.x);
  o[1] = (__bf16)((v.y - mean) * rstd * gg.y + bb.y);
  *(bf2_t*)&out[(size_t)row * ND + lane * 2] = o;
}

// ---------------- bf16 MFMA GEMM: C[M,Nc] = X[M,K] @ W[Nc,K]^T + bias ----------------
// Block tile 32x64; 4 waves in 2x2, each 16x32 via mfma_f32_16x16x32_bf16.
// Whole BK=128 staged per barrier; LDS rows padded to 136 bf16 (272B) -> bank-
// group (row+4kk+q) mod 8 balanced at the b128 structural minimum.
// mode 0: fp32 C (+res). mode 1: gelu -> bf16 Cb (ldc=Nc). mode 2: qkv pack.
__global__ __launch_bounds__(256) void bgemm_kernel(
    const __bf16* __restrict__ X, const __bf16* __restrict__ Wt,
    const float* __restrict__ bias, const float* __restrict__ res,
    float* __restrict__ C, __bf16* __restrict__ Cb,
    __bf16* __restrict__ Qb, __bf16* __restrict__ Kb, __bf16* __restrict__ Vt,
    int K, int Nc, int mode) {
  __shared__ __bf16 Xs[32][136];
  __shared__ __bf16 Ws[64][136];
  int m0 = blockIdx.y * 32, n0 = blockIdx.x * 64;
  int t = threadIdx.x;
  int lane = t & 63, wave = t >> 6;
  int l15 = lane & 15, quad = lane >> 4;
  int wm = (wave >> 1) * 16, wn = (wave & 1) * 32;
  f4x acc0 = {0.f, 0.f, 0.f, 0.f}, acc1 = {0.f, 0.f, 0.f, 0.f};
  for (int ks = 0; ks < K; ks += 128) {
    if (ks) __syncthreads();
#pragma unroll
    for (int c = t; c < 512; c += 256) {
      int r = c >> 4, ch = c & 15;
      *(bf8_t*)&Xs[r][ch * 8] = *(const bf8_t*)&X[(size_t)(m0 + r) * K + ks + ch * 8];
    }
#pragma unroll
    for (int c = t; c < 1024; c += 256) {
      int r = c >> 4, ch = c & 15;
      *(bf8_t*)&Ws[r][ch * 8] = *(const bf8_t*)&Wt[(size_t)(n0 + r) * K + ks + ch * 8];
    }
    __syncthreads();
#pragma unroll
    for (int kk = 0; kk < 4; kk++) {
      bf8_t a  = *(const bf8_t*)&Xs[wm + l15][kk * 32 + quad * 8];
      bf8_t b0 = *(const bf8_t*)&Ws[wn + l15][kk * 32 + quad * 8];
      bf8_t b1 = *(const bf8_t*)&Ws[wn + 16 + l15][kk * 32 + quad * 8];
      acc0 = __builtin_amdgcn_mfma_f32_16x16x32_bf16(a, b0, acc0, 0, 0, 0);
      acc1 = __builtin_amdgcn_mfma_f32_16x16x32_bf16(a, b1, acc1, 0, 0, 0);
    }
  }
  // epilogue: C/D layout col=l15, row=quad*4+reg
#pragma unroll
  for (int nf = 0; nf < 2; nf++) {
    const f4x& acc = nf ? acc1 : acc0;
    int n = n0 + wn + nf * 16 + l15;
    float bv = bias[n];
#pragma unroll
    for (int r = 0; r < 4; r++) {
      int m = m0 + wm + quad * 4 + r;
      float v = acc[r] + bv;
      if (mode == 0) {
        if (res) v += res[(size_t)m * ND + n];
        C[(size_t)m * ND + n] = v;
      } else if (mode == 1) {
        v = 0.5f * v * (1.0f + erff(v * 0.70710678118f));
        Cb[(size_t)m * Nc + n] = (__bf16)v;
      } else {
        if (n < ND) Qb[(size_t)m * ND + n] = (__bf16)v;
        else if (n < 2 * ND) Kb[(size_t)m * ND + n - ND] = (__bf16)v;
        else {
          int c = n - 2 * ND, hh = c >> 4, d0 = c & 15;
          int bb = m >> 11, nn = m & 2047;
          Vt[((size_t)((bb * NH + hh) * NDH + d0)) * NN + nn] = (__bf16)v;
        }
      }
    }
  }
}

// ---------------- MFMA flash attention (no-max softmax, key-split) ----------------
__global__ __launch_bounds__(256) void attn_kernel(
    const __bf16* __restrict__ Qb, const __bf16* __restrict__ Kb,
    const __bf16* __restrict__ Vt, const unsigned int* __restrict__ adjbits,
    const unsigned int* __restrict__ maskbits, const int* __restrict__ mask,
    const float* __restrict__ sbias, int layer, __bf16* __restrict__ o) {
  int b = blockIdx.z, hh = blockIdx.y, q0 = blockIdx.x * 16;
  int wave = threadIdx.x >> 6;
  int lane = threadIdx.x & 63;
  int l15 = lane & 15, quad = lane >> 4;
  float sb = sbias[layer];
  float esb = __expf(sb);
  const int bN = b * NN;
  const int kw0 = wave * 512;

  __shared__ __bf16 Pbuf[4][16][40];
  __shared__ float Ored[4][16][17];
  __shared__ float Lred[4][16];

  bf8_t Af;
  if (quad < 2) {
    Af = *(const bf8_t*)(Qb + (size_t)(bN + q0 + l15) * ND + hh * NDH + quad * 8);
  } else {
#pragma unroll
    for (int j = 0; j < 8; j++) Af[j] = (__bf16)0.f;
  }

  int qrow[4], mq[4];
  const unsigned int* adjp[4];
#pragma unroll
  for (int r = 0; r < 4; r++) {
    qrow[r] = q0 + quad * 4 + r;
    mq[r] = mask[bN + qrow[r]];
    adjp[r] = adjbits + (size_t)(bN + qrow[r]) * (NN / 32) + (kw0 >> 5);
  }
  const unsigned int* mbp = maskbits + (bN + kw0) / 32;
  const __bf16* kp = Kb + (size_t)(bN + kw0 + l15) * ND + hh * NDH + quad * 8;
  const __bf16* vp = Vt + (size_t)((b * NH + hh) * NDH + l15) * NN + kw0 + quad * 8;

  f4x O = {0.f, 0.f, 0.f, 0.f};
  float ls[4] = {0.f, 0.f, 0.f, 0.f};

  for (int t = 0; t < 16; t++) {
    bf8_t K0, K1;
    if (quad < 2) {
      K0 = *(const bf8_t*)kp;
      K1 = *(const bf8_t*)(kp + 16 * ND);
    } else {
#pragma unroll
      for (int j = 0; j < 8; j++) { K0[j] = (__bf16)0.f; K1[j] = (__bf16)0.f; }
    }
    bf8_t Vf = *(const bf8_t*)(vp + t * 32);
    f4x z = {0.f, 0.f, 0.f, 0.f};
    f4x S0 = __builtin_amdgcn_mfma_f32_16x16x32_bf16(Af, K0, z, 0, 0, 0);
    f4x S1 = __builtin_amdgcn_mfma_f32_16x16x32_bf16(Af, K1, z, 0, 0, 0);
    unsigned int mkw = mbp[t];
    unsigned int aw[4] = {adjp[0][t], adjp[1][t], adjp[2][t], adjp[3][t]};
    int kb = kw0 + t * 32;
#pragma unroll
    for (int s = 0; s < 2; s++) {
      int bitpos = s * 16 + l15;
      int j = kb + bitpos;
      int mj = (mkw >> bitpos) & 1;
      const f4x& S = s ? S1 : S0;
#pragma unroll
      for (int r = 0; r < 4; r++) {
        float e = __expf(S[r] * ATT_SCALE);
        float f = ((aw[r] >> bitpos) & 1) ? esb : 1.0f;
        bool ok = mq[r] ? (mj != 0) : (j == qrow[r]);
        float p = ok ? e * f : 0.f;
        ls[r] += p;
        Pbuf[wave][quad * 4 + r][bitpos] = (__bf16)p;
      }
    }
    asm volatile("s_waitcnt lgkmcnt(0)" ::: "memory");
    bf8_t Pf = *(const bf8_t*)&Pbuf[wave][l15][quad * 8];
    O = __builtin_amdgcn_mfma_f32_16x16x32_bf16(Pf, Vf, O, 0, 0, 0);
    kp += 32 * ND;
  }

#pragma unroll
  for (int r = 0; r < 4; r++) {
    float v = ls[r];
    v += __shfl_xor(v, 1, 64);
    v += __shfl_xor(v, 2, 64);
    v += __shfl_xor(v, 4, 64);
    v += __shfl_xor(v, 8, 64);
    if (l15 == 0) Lred[wave][quad * 4 + r] = v;
    Ored[wave][quad * 4 + r][l15] = O[r];
  }
  __syncthreads();
  int row = threadIdx.x >> 4, col = threadIdx.x & 15;
  float s = Ored[0][row][col] + Ored[1][row][col] + Ored[2][row][col] + Ored[3][row][col];
  float L = Lred[0][row] + Lred[1][row] + Lred[2][row] + Lred[3][row];
  o[(size_t)(bN + q0 + row) * ND + hh * NDH + col] = (__bf16)(s / L);
}

// ---------------- head: pool root row, LN, dot with head_w ----------------
__global__ void head_kernel(const float* __restrict__ h, const int* __restrict__ root_idx,
                            const float* __restrict__ g, const float* __restrict__ bt,
                            const float* __restrict__ hw, const float* __restrict__ hb,
                            float* __restrict__ out) {
  int b = blockIdx.x, lane = threadIdx.x;  // 64 threads
  const float* row = h + ((size_t)b * NN + root_idx[b]) * ND;
  float2 v = *(const float2*)&row[lane * 2];
  float s1 = v.x + v.y, s2 = v.x * v.x + v.y * v.y;
#pragma unroll
  for (int m = 32; m >= 1; m >>= 1) {
    s1 += __shfl_xor(s1, m, 64);
    s2 += __shfl_xor(s2, m, 64);
  }
  float mean = s1 * (1.0f / ND);
  float var = s2 * (1.0f / ND) - mean * mean;
  float rstd = rsqrtf(var + LN_EPS);
  float p0 = (v.x - mean) * rstd * g[lane * 2] + bt[lane * 2];
  float p1 = (v.y - mean) * rstd * g[lane * 2 + 1] + bt[lane * 2 + 1];
  float part = p0 * hw[lane * 2] + p1 * hw[lane * 2 + 1];
#pragma unroll
  for (int m = 32; m >= 1; m >>= 1) part += __shfl_xor(part, m, 64);
  if (lane == 0) out[b] = part + hb[0];
}

extern "C" void kernel_launch(void* const* d_in, const int* in_sizes, int n_in,
                              void* d_out, int out_size, void* d_ws, size_t ws_size,
                              hipStream_t stream) {
  const float* atom_embed = (const float*)d_in[0];
  const float* cons_embed = (const float*)d_in[1];
  const float* in_w  = (const float*)d_in[2];
  const float* in_b  = (const float*)d_in[3];
  const float* qkv_w = (const float*)d_in[4];
  const float* qkv_b = (const float*)d_in[5];
  const float* out_w = (const float*)d_in[6];
  const float* out_b = (const float*)d_in[7];
  const float* ln1_g = (const float*)d_in[8];
  const float* ln1_b = (const float*)d_in[9];
  const float* ln2_g = (const float*)d_in[10];
  const float* ln2_b = (const float*)d_in[11];
  const float* ff1_w = (const float*)d_in[12];
  const float* ff1_b = (const float*)d_in[13];
  const float* ff2_w = (const float*)d_in[14];
  const float* ff2_b = (const float*)d_in[15];
  const float* sbias = (const float*)d_in[16];
  const float* hg    = (const float*)d_in[17];
  const float* hbt   = (const float*)d_in[18];
  const float* hw    = (const float*)d_in[19];
  const float* hb    = (const float*)d_in[20];
  const float* adj   = (const float*)d_in[21];
  const int* is_atom = (const int*)d_in[22];
  const int* atom_id = (const int*)d_in[23];
  const int* mask    = (const int*)d_in[24];
  const int* root_idx= (const int*)d_in[25];
  float* out = (float*)d_out;

  const int MR = NB * NN;  // 4096 rows
  float* h = (float*)d_ws;                      // 524288 f
  __bf16* xb   = (__bf16*)(h + MR * ND);        // 524288
  __bf16* ob   = xb + MR * ND;                  // 524288
  __bf16* fb   = ob + MR * ND;                  // 2097152
  __bf16* Qb   = fb + MR * 512;                 // 524288
  __bf16* Kb   = Qb + MR * ND;                  // 524288
  __bf16* Vt   = Kb + MR * ND;                  // 524288
  __bf16* wbin = Vt + MR * ND;                  // 16384
  __bf16* wbqkv= wbin + ND * ND;                // 147456
  __bf16* wbout= wbqkv + NL * 384 * ND;         // 49152
  __bf16* wbff1= wbout + NL * ND * ND;          // 196608
  __bf16* wbff2= wbff1 + NL * 512 * ND;         // 196608
  unsigned int* adjb = (unsigned int*)(wbff2 + NL * ND * 512);
  unsigned int* mskb = adjb + NB * NN * NN / 32;

  castbf_kernel<<<16, 256, 0, stream>>>(in_w, wbin, 4096);
  castbf_kernel<<<144, 256, 0, stream>>>(qkv_w, wbqkv, 36864);
  castbf_kernel<<<48, 256, 0, stream>>>(out_w, wbout, 12288);
  castbf_kernel<<<192, 256, 0, stream>>>(ff1_w, wbff1, 49152);
  castbf_kernel<<<192, 256, 0, stream>>>(ff2_w, wbff2, 49152);
  adjbits_kernel<<<NB * NN * NN / 64 / 4, 256, 0, stream>>>(adj, (unsigned long long*)adjb);
  maskbits_kernel<<<16, 256, 0, stream>>>(mask, (unsigned long long*)mskb);
  embed_kernel<<<MR * ND / 256, 256, 0, stream>>>(atom_embed, cons_embed, is_atom, atom_id, xb);

  bgemm_kernel<<<dim3(2, MR / 32), 256, 0, stream>>>(
      xb, wbin, in_b, nullptr, h, nullptr, nullptr, nullptr, nullptr, ND, ND, 0);

  for (int i = 0; i < NL; i++) {
    ln_kernel<<<MR / 4, 256, 0, stream>>>(h, xb, ln1_g + i * ND, ln1_b + i * ND);
    bgemm_kernel<<<dim3(6, MR / 32), 256, 0, stream>>>(
        xb, wbqkv + (size_t)i * 384 * ND, qkv_b + i * 384, nullptr, nullptr,
        nullptr, Qb, Kb, Vt, ND, 384, 2);
    attn_kernel<<<dim3(NN / 16, NH, NB), 256, 0, stream>>>(
        Qb, Kb, Vt, adjb, mskb, mask, sbias, i, ob);
    bgemm_kernel<<<dim3(2, MR / 32), 256, 0, stream>>>(
        ob, wbout + (size_t)i * ND * ND, out_b + i * ND, h, h, nullptr,
        nullptr, nullptr, nullptr, ND, ND, 0);
    ln_kernel<<<MR / 4, 256, 0, stream>>>(h, xb, ln2_g + i * ND, ln2_b + i * ND);
    bgemm_kernel<<<dim3(8, MR / 32), 256, 0, stream>>>(
        xb, wbff1 + (size_t)i * 512 * ND, ff1_b + i * 512, nullptr, nullptr, fb,
        nullptr, nullptr, nullptr, ND, 512, 1);
    bgemm_kernel<<<dim3(2, MR / 32), 256, 0, stream>>>(
        fb, wbff2 + (size_t)i * ND * 512, ff2_b + i * ND, h, h, nullptr,
        nullptr, nullptr, nullptr, 512, ND, 0);
  }
  head_kernel<<<NB, 64, 0, stream>>>(h, root_idx, hg, hbt, hw, hb, out);
}